// Round 1
// baseline (132.279 us; speedup 1.0000x reference)
//
#include <hip/hip_runtime.h>

// Problem constants (fixed by harness setup)
#define BB 32
#define KK 5
#define TT 20
#define VV 9488
#define HH 1024

// Output layout (floats), concatenated in return order:
// out0 beam_seq          : [0,                3360)
// out1 beam_seq_logprobs : [3360,             31883040)   (32*5*21*9488)
// out2 beam_logprobs_sum : [31883040,         31883200)
// out3 new_state         : [31883200,         32210880)
#define OFF1 3360
#define OFF2 31883040
#define OFF3 31883200

__device__ __forceinline__ bool better(float av, int ai, float bv, int bi) {
    // total order: value descending, then index ascending (jax top_k tie-break)
    return (av > bv) || (av == bv && ai < bi);
}

__global__ __launch_bounds__(256) void topk_kernel(
    const float* __restrict__ logprobs,      // (B*K, V)
    const float* __restrict__ sums,          // (B, K)
    int* __restrict__ ws_beam,               // (B*K)
    int* __restrict__ ws_sel,                // (B*K)
    float* __restrict__ ws_sum)              // (B*K)
{
    const int b   = blockIdx.x;
    const int tid = threadIdx.x;

    float tv[5]; int ti[5];
#pragma unroll
    for (int j = 0; j < 5; ++j) { tv[j] = -INFINITY; ti[j] = 0x7fffffff; }

    // local scan: candidate (k, v) -> sums[b][k] + logprobs[b*K+k][v]
    for (int k = 0; k < KK; ++k) {
        const float s = sums[b * KK + k];
        const float* lp = logprobs + (size_t)(b * KK + k) * VV;
        for (int v = tid; v < VV; v += 256) {
            const float val = s + lp[v];
            const int idx = k * VV + v;
            if (better(val, idx, tv[4], ti[4])) {
                int pos = 4;
#pragma unroll
                for (int j = 3; j >= 0; --j)
                    if (better(val, idx, tv[j], ti[j])) pos = j;
#pragma unroll
                for (int j = 4; j > 0; --j) {
                    if (j > pos) { tv[j] = tv[j-1]; ti[j] = ti[j-1]; }
                }
                tv[pos] = val; ti[pos] = idx;
            }
        }
    }

    __shared__ float sv[256 * 5];
    __shared__ int   si[256 * 5];

    // tournament merge of sorted-5 lists
    for (int stride = 128; stride >= 1; stride >>= 1) {
        if (tid >= stride && tid < 2 * stride) {
#pragma unroll
            for (int j = 0; j < 5; ++j) { sv[tid*5+j] = tv[j]; si[tid*5+j] = ti[j]; }
        }
        __syncthreads();
        if (tid < stride) {
            float bv[5]; int bi[5];
#pragma unroll
            for (int j = 0; j < 5; ++j) { bv[j] = sv[(tid+stride)*5+j]; bi[j] = si[(tid+stride)*5+j]; }
            float ov[5]; int oi[5];
            int ia = 0, ib = 0;
#pragma unroll
            for (int n = 0; n < 5; ++n) {
                if (better(tv[ia], ti[ia], bv[ib], bi[ib])) { ov[n] = tv[ia]; oi[n] = ti[ia]; ++ia; }
                else                                        { ov[n] = bv[ib]; oi[n] = bi[ib]; ++ib; }
            }
#pragma unroll
            for (int j = 0; j < 5; ++j) { tv[j] = ov[j]; ti[j] = oi[j]; }
        }
        __syncthreads();
    }

    if (tid == 0) {
#pragma unroll
        for (int j = 0; j < 5; ++j) {
            const int idx  = ti[j];
            const int beam = idx / VV;
            const int sel  = idx - beam * VV;
            ws_beam[b * KK + j] = beam;
            ws_sel [b * KK + j] = sel;
            ws_sum [b * KK + j] = tv[j];
        }
    }
}

__global__ __launch_bounds__(256) void scatter_kernel(
    const float* __restrict__ logprobs,      // (B*K, V)
    const int*   __restrict__ beam_seq_in,   // (B, K, T)
    const float* __restrict__ bslp_in,       // (B, K, T, V)
    const float* __restrict__ state_in,      // (2, B*K, H)
    const int*   __restrict__ ws_beam,
    const int*   __restrict__ ws_sel,
    const float* __restrict__ ws_sum,
    float* __restrict__ out)
{
    const int bid = blockIdx.x;
    const int tid = threadIdx.x;
    const int NROWS = BB * KK * (TT + 1);    // 3360

    if (bid < NROWS) {
        // one 9488-float row of beam_seq_logprobs output
        const int b   = bid / (KK * (TT + 1));
        const int rem = bid % (KK * (TT + 1));
        const int k   = rem / (TT + 1);
        const int t   = rem % (TT + 1);
        const int beam = ws_beam[b * KK + k];
        const float* src;
        if (t < TT) src = bslp_in + ((size_t)((b * KK + beam) * TT + t)) * VV;
        else        src = logprobs + (size_t)(b * KK + beam) * VV;
        float* dst = out + OFF1 + (size_t)bid * VV;
        const float4* s4 = (const float4*)src;
        float4* d4 = (float4*)dst;
        for (int i = tid; i < VV / 4; i += 256) d4[i] = s4[i];
    } else if (bid < NROWS + 2 * BB * KK) {
        // one 1024-float row of new_state
        const int r = bid - NROWS;
        const int s = r / (BB * KK);
        const int i = r % (BB * KK);
        const int b = i / KK;
        const int beam = ws_beam[i];
        const float4* s4 = (const float4*)(state_in + ((size_t)s * (BB * KK) + b * KK + beam) * HH);
        float4* d4 = (float4*)(out + OFF3 + (size_t)r * HH);
        for (int j = tid; j < HH / 4; j += 256) d4[j] = s4[j];
    } else {
        // small outputs: beam_seq (as float) and beam_logprobs_sum
        for (int j = tid; j < NROWS; j += 256) {
            const int b   = j / (KK * (TT + 1));
            const int rem = j % (KK * (TT + 1));
            const int k   = rem / (TT + 1);
            const int t   = rem % (TT + 1);
            const int bk  = b * KK + k;
            int val;
            if (t < TT) val = beam_seq_in[(size_t)(b * KK + ws_beam[bk]) * TT + t];
            else        val = ws_sel[bk];
            out[j] = (float)val;
        }
        for (int j = tid; j < BB * KK; j += 256) out[OFF2 + j] = ws_sum[j];
    }
}

extern "C" void kernel_launch(void* const* d_in, const int* in_sizes, int n_in,
                              void* d_out, int out_size, void* d_ws, size_t ws_size,
                              hipStream_t stream) {
    const float* logprobs    = (const float*)d_in[0];
    const int*   beam_seq    = (const int*)  d_in[1];
    const float* bslp        = (const float*)d_in[2];
    const float* sums        = (const float*)d_in[3];
    const float* state       = (const float*)d_in[4];

    int*   ws_beam = (int*)d_ws;
    int*   ws_sel  = ws_beam + BB * KK;
    float* ws_sum  = (float*)(ws_sel + BB * KK);
    float* out     = (float*)d_out;

    topk_kernel<<<BB, 256, 0, stream>>>(logprobs, sums, ws_beam, ws_sel, ws_sum);

    const int nblocks = BB * KK * (TT + 1) + 2 * BB * KK + 1;  // 3681
    scatter_kernel<<<nblocks, 256, 0, stream>>>(logprobs, beam_seq, bslp, state,
                                                ws_beam, ws_sel, ws_sum, out);
}

// Round 2
// 61.938 us; speedup vs baseline: 2.1357x; 2.1357x over previous
//
#include <hip/hip_runtime.h>

// Problem constants (fixed by harness setup)
#define BB 32
#define KK 5
#define TT 20
#define VV 9488
#define HH 1024

#define NSPLIT 16
#define CHUNK (VV / NSPLIT)   // 593 (exact: 16*593 = 9488)

// Output layout (floats), concatenated in return order:
// out0 beam_seq          : [0,                3360)
// out1 beam_seq_logprobs : [3360,             31883040)   (32*5*21*9488)
// out2 beam_logprobs_sum : [31883040,         31883200)
// out3 new_state         : [31883200,         32210880)
#define OFF1 3360
#define OFF2 31883040
#define OFF3 31883200

__device__ __forceinline__ bool better(float av, int ai, float bv, int bi) {
    // total order: value descending, then index ascending (jax top_k tie-break)
    return (av > bv) || (av == bv && ai < bi);
}

// Phase 1: 512 blocks; each handles one (batch, v-slice) over all 5 beams.
__global__ __launch_bounds__(256) void topk_part_kernel(
    const float* __restrict__ logprobs,      // (B*K, V)
    const float* __restrict__ sums,          // (B, K)
    float* __restrict__ pv,                  // (B*NSPLIT*5)
    int*   __restrict__ pi)
{
    const int b    = blockIdx.x / NSPLIT;
    const int part = blockIdx.x % NSPLIT;
    const int tid  = threadIdx.x;
    const int v0   = part * CHUNK;

    float tv[5]; int ti[5];
#pragma unroll
    for (int j = 0; j < 5; ++j) { tv[j] = -INFINITY; ti[j] = 0x7fffffff; }

    for (int k = 0; k < KK; ++k) {
        const float s = sums[b * KK + k];
        const float* lp = logprobs + (size_t)(b * KK + k) * VV;
        for (int v = v0 + tid; v < v0 + CHUNK; v += 256) {
            const float val = s + lp[v];
            const int idx = k * VV + v;
            if (better(val, idx, tv[4], ti[4])) {
                int pos = 4;
#pragma unroll
                for (int j = 3; j >= 0; --j)
                    if (better(val, idx, tv[j], ti[j])) pos = j;
#pragma unroll
                for (int j = 4; j > 0; --j) {
                    if (j > pos) { tv[j] = tv[j-1]; ti[j] = ti[j-1]; }
                }
                tv[pos] = val; ti[pos] = idx;
            }
        }
    }

    __shared__ float sv[256 * 5];
    __shared__ int   si[256 * 5];

    // tournament merge of sorted-5 lists
    for (int stride = 128; stride >= 1; stride >>= 1) {
        if (tid >= stride && tid < 2 * stride) {
#pragma unroll
            for (int j = 0; j < 5; ++j) { sv[tid*5+j] = tv[j]; si[tid*5+j] = ti[j]; }
        }
        __syncthreads();
        if (tid < stride) {
            float bv[5]; int bi[5];
#pragma unroll
            for (int j = 0; j < 5; ++j) { bv[j] = sv[(tid+stride)*5+j]; bi[j] = si[(tid+stride)*5+j]; }
            float ov[5]; int oi[5];
            int ia = 0, ib = 0;
#pragma unroll
            for (int n = 0; n < 5; ++n) {
                if (better(tv[ia], ti[ia], bv[ib], bi[ib])) { ov[n] = tv[ia]; oi[n] = ti[ia]; ++ia; }
                else                                        { ov[n] = bv[ib]; oi[n] = bi[ib]; ++ib; }
            }
#pragma unroll
            for (int j = 0; j < 5; ++j) { tv[j] = ov[j]; ti[j] = oi[j]; }
        }
        __syncthreads();
    }

    if (tid == 0) {
#pragma unroll
        for (int j = 0; j < 5; ++j) {
            pv[(size_t)blockIdx.x * 5 + j] = tv[j];
            pi[(size_t)blockIdx.x * 5 + j] = ti[j];
        }
    }
}

// Phase 2: 32 blocks; merge NSPLIT sorted-5 lists -> final top-5 per batch.
__global__ __launch_bounds__(64) void topk_merge_kernel(
    const float* __restrict__ pv,
    const int*   __restrict__ pi,
    int* __restrict__ ws_beam,
    int* __restrict__ ws_sel,
    float* __restrict__ ws_sum)
{
    const int b   = blockIdx.x;
    const int tid = threadIdx.x;

    float tv[5]; int ti[5];
    if (tid < NSPLIT) {
#pragma unroll
        for (int j = 0; j < 5; ++j) {
            tv[j] = pv[((size_t)b * NSPLIT + tid) * 5 + j];
            ti[j] = pi[((size_t)b * NSPLIT + tid) * 5 + j];
        }
    } else {
#pragma unroll
        for (int j = 0; j < 5; ++j) { tv[j] = -INFINITY; ti[j] = 0x7fffffff; }
    }

    __shared__ float sv[NSPLIT * 5];
    __shared__ int   si[NSPLIT * 5];

    for (int stride = NSPLIT / 2; stride >= 1; stride >>= 1) {
        if (tid >= stride && tid < 2 * stride) {
#pragma unroll
            for (int j = 0; j < 5; ++j) { sv[tid*5+j] = tv[j]; si[tid*5+j] = ti[j]; }
        }
        __syncthreads();
        if (tid < stride) {
            float bv[5]; int bi[5];
#pragma unroll
            for (int j = 0; j < 5; ++j) { bv[j] = sv[(tid+stride)*5+j]; bi[j] = si[(tid+stride)*5+j]; }
            float ov[5]; int oi[5];
            int ia = 0, ib = 0;
#pragma unroll
            for (int n = 0; n < 5; ++n) {
                if (better(tv[ia], ti[ia], bv[ib], bi[ib])) { ov[n] = tv[ia]; oi[n] = ti[ia]; ++ia; }
                else                                        { ov[n] = bv[ib]; oi[n] = bi[ib]; ++ib; }
            }
#pragma unroll
            for (int j = 0; j < 5; ++j) { tv[j] = ov[j]; ti[j] = oi[j]; }
        }
        __syncthreads();
    }

    if (tid == 0) {
#pragma unroll
        for (int j = 0; j < 5; ++j) {
            const int idx  = ti[j];
            const int beam = idx / VV;
            const int sel  = idx - beam * VV;
            ws_beam[b * KK + j] = beam;
            ws_sel [b * KK + j] = sel;
            ws_sum [b * KK + j] = tv[j];
        }
    }
}

__global__ __launch_bounds__(256) void scatter_kernel(
    const float* __restrict__ logprobs,      // (B*K, V)
    const int*   __restrict__ beam_seq_in,   // (B, K, T)
    const float* __restrict__ bslp_in,       // (B, K, T, V)
    const float* __restrict__ state_in,      // (2, B*K, H)
    const int*   __restrict__ ws_beam,
    const int*   __restrict__ ws_sel,
    const float* __restrict__ ws_sum,
    float* __restrict__ out)
{
    const int bid = blockIdx.x;
    const int tid = threadIdx.x;
    const int NROWS = BB * KK * (TT + 1);    // 3360

    if (bid < NROWS) {
        // one 9488-float row of beam_seq_logprobs output
        const int b   = bid / (KK * (TT + 1));
        const int rem = bid % (KK * (TT + 1));
        const int k   = rem / (TT + 1);
        const int t   = rem % (TT + 1);
        const int beam = ws_beam[b * KK + k];
        const float* src;
        if (t < TT) src = bslp_in + ((size_t)((b * KK + beam) * TT + t)) * VV;
        else        src = logprobs + (size_t)(b * KK + beam) * VV;
        float* dst = out + OFF1 + (size_t)bid * VV;
        const float4* s4 = (const float4*)src;
        float4* d4 = (float4*)dst;
        for (int i = tid; i < VV / 4; i += 256) d4[i] = s4[i];
    } else if (bid < NROWS + 2 * BB * KK) {
        // one 1024-float row of new_state
        const int r = bid - NROWS;
        const int s = r / (BB * KK);
        const int i = r % (BB * KK);
        const int b = i / KK;
        const int beam = ws_beam[i];
        const float4* s4 = (const float4*)(state_in + ((size_t)s * (BB * KK) + b * KK + beam) * HH);
        float4* d4 = (float4*)(out + OFF3 + (size_t)r * HH);
        for (int j = tid; j < HH / 4; j += 256) d4[j] = s4[j];
    } else {
        // small outputs: beam_seq (as float) and beam_logprobs_sum
        for (int j = tid; j < NROWS; j += 256) {
            const int b   = j / (KK * (TT + 1));
            const int rem = j % (KK * (TT + 1));
            const int k   = rem / (TT + 1);
            const int t   = rem % (TT + 1);
            const int bk  = b * KK + k;
            int val;
            if (t < TT) val = beam_seq_in[(size_t)(b * KK + ws_beam[bk]) * TT + t];
            else        val = ws_sel[bk];
            out[j] = (float)val;
        }
        for (int j = tid; j < BB * KK; j += 256) out[OFF2 + j] = ws_sum[j];
    }
}

extern "C" void kernel_launch(void* const* d_in, const int* in_sizes, int n_in,
                              void* d_out, int out_size, void* d_ws, size_t ws_size,
                              hipStream_t stream) {
    const float* logprobs    = (const float*)d_in[0];
    const int*   beam_seq    = (const int*)  d_in[1];
    const float* bslp        = (const float*)d_in[2];
    const float* sums        = (const float*)d_in[3];
    const float* state       = (const float*)d_in[4];

    int*   ws_beam = (int*)d_ws;
    int*   ws_sel  = ws_beam + BB * KK;
    float* ws_sum  = (float*)(ws_sel + BB * KK);
    float* pv      = ws_sum + BB * KK;
    int*   pi      = (int*)(pv + BB * NSPLIT * 5);
    float* out     = (float*)d_out;

    topk_part_kernel<<<BB * NSPLIT, 256, 0, stream>>>(logprobs, sums, pv, pi);
    topk_merge_kernel<<<BB, 64, 0, stream>>>(pv, pi, ws_beam, ws_sel, ws_sum);

    const int nblocks = BB * KK * (TT + 1) + 2 * BB * KK + 1;  // 3681
    scatter_kernel<<<nblocks, 256, 0, stream>>>(logprobs, beam_seq, bslp, state,
                                                ws_beam, ws_sel, ws_sum, out);
}